// Round 4
// baseline (298.308 us; speedup 1.0000x reference)
//
#include <hip/hip_runtime.h>
#include <hip/hip_cooperative_groups.h>
#include <math.h>

namespace cg = cooperative_groups;

// Problem: X[16384,64] fp32, W[8192,64] fp32 -> argmin_c ||x-w_c||^2 (int32)
#define EMB     64
#define NTOK    8192
#define NQ      16384
#define TPB     256               // 4 waves: 2 q-halves x 2 c-halves
#define CSPLIT  4
#define CRANGE  (NTOK / CSPLIT)   // 2048 codewords per y-split
#define NT      (CRANGE / 128)    // 16 tiles
#define BQ      128               // query rows per block
#define TILE_C  128               // codewords staged in LDS per iteration
#define TCH     (TILE_C * EMB)    // halves per tile buffer (8192 = 16KB)
#define NXBLK   (NQ / BQ)         // 128
#define NGRID   (NXBLK * CSPLIT)  // 512 blocks = 2/CU x 256 CU (co-resident)

typedef _Float16 half8 __attribute__((ext_vector_type(8)));
typedef float    f32x4 __attribute__((ext_vector_type(4)));

// async global->LDS DMA, 16B per lane (dest = wave-uniform base + lane*16)
__device__ __forceinline__ void gl2lds16(const _Float16* g, _Float16* l) {
    __builtin_amdgcn_global_load_lds(
        (const __attribute__((address_space(1))) unsigned int*)g,
        (__attribute__((address_space(3))) unsigned int*)l, 16, 0, 0);
}

// ---------------------------------------------------------------------------
// Prep phase: split W into fp16 hi + lo in MFMA-FRAGMENT ORDER, + ||w_c||^2.
// Chunk u (16B = 8 halves): u = g*128 + kb*64 + lq*16 + r, c = g*16+r,
// k0 = kb*32 + lq*8. Thread-per-chunk for the split (gtid < 65536);
// thread-per-row for ynorm (next 8192 gtids). Same accumulation order as
// the verified kernels -> bit-identical Wh/Wl/ynorm.
// ---------------------------------------------------------------------------
__device__ __forceinline__ void vq_prep_phase(
    int gtid, const float* __restrict__ W,
    _Float16* __restrict__ Wh, _Float16* __restrict__ Wl,
    float* __restrict__ ynorm)
{
    if (gtid < NTOK * 8) {
        const int u = gtid;
        const int g = u >> 7, rem = u & 127;
        const int kb = rem >> 6, ln = rem & 63;
        const int r = ln & 15, lq2 = ln >> 4;
        const int c = g * 16 + r;
        const int k0 = kb * 32 + lq2 * 8;
        const float* wp = W + (size_t)c * EMB + k0;
        float4 v0 = *(const float4*)wp;
        float4 v1 = *(const float4*)(wp + 4);
        float xv[8] = {v0.x, v0.y, v0.z, v0.w, v1.x, v1.y, v1.z, v1.w};
        half8 h, l;
#pragma unroll
        for (int j = 0; j < 8; ++j) {
            _Float16 hh = (_Float16)xv[j];
            h[j] = hh;
            l[j] = (_Float16)(xv[j] - (float)hh);
        }
        *(half8*)(Wh + (size_t)u * 8) = h;
        *(half8*)(Wl + (size_t)u * 8) = l;
    } else if (gtid < NTOK * 8 + NTOK) {
        const int c = gtid - NTOK * 8;
        const float4* w4 = (const float4*)(W + (size_t)c * EMB);
        float s = 0.f;
#pragma unroll
        for (int i = 0; i < EMB / 4; ++i) {
            float4 v = w4[i];
            s = fmaf(v.x, v.x, s); s = fmaf(v.y, v.y, s);
            s = fmaf(v.z, v.z, s); s = fmaf(v.w, v.w, s);
        }
        ynorm[c] = s;
    }
}

// ---------------------------------------------------------------------------
// Main phase: fp16x4-split MFMA distance + argmin, 2-phase pipelined staging.
// Round-1 winning shape: 4 waves = 2(q-half: 64 rows) x 2(c-half: 64 cols).
// Per tile: STAGE(t+1) async DMA -> 4 ct phases {setprio(1)+32 MFMA+
// setprio(0); prefetch next ct ds_reads; epilogue VALU} -> vmcnt(0)+
// lgkmcnt(0)+s_barrier. Numerics identical to all passing versions.
// ---------------------------------------------------------------------------
__device__ __forceinline__ void vq_main_phase(
    int bx, int by,
    const float* __restrict__ X,
    const _Float16* __restrict__ Wh, const _Float16* __restrict__ Wl,
    const float* __restrict__ ynorm,
    float* __restrict__ pval, int* __restrict__ pidx)
{
    __shared__ __align__(16) _Float16 LdsH0[TCH];
    __shared__ __align__(16) _Float16 LdsH1[TCH];
    __shared__ __align__(16) _Float16 LdsL0[TCH];
    __shared__ __align__(16) _Float16 LdsL1[TCH];
    __shared__ __align__(16) float    Lyn[CRANGE];
    __shared__ float RedV[2][BQ];
    __shared__ int   RedI[2][BQ];

    const int t    = threadIdx.x;
    const int lane = t & 63;
    const int wid  = t >> 6;       // 0..3
    const int wq   = wid & 1;      // q half (0/1)
    const int wy   = wid >> 1;     // c half (0/1)
    const int l15  = lane & 15;
    const int lq   = lane >> 4;    // 0..3

    const int qblk   = bx * BQ;
    const int qbase  = qblk + wq * 64;
    const int cbase0 = by * CRANGE;

    // --- issue tile-0 DMA first so it overlaps prologue work ---
    {
        const size_t gsbase = (size_t)(cbase0 >> 4) * 1024;   // halves
#pragma unroll
        for (int i = 0; i < 4; ++i) {
            const int jw = i * 256 + wid * 64;                // wave-uniform chunk base
            gl2lds16(Wh + gsbase + (size_t)(jw + lane) * 8, LdsH0 + (size_t)jw * 8);
            gl2lds16(Wl + gsbase + (size_t)(jw + lane) * 8, LdsL0 + (size_t)jw * 8);
        }
    }

    // --- stage the block's full ynorm range once ---
    for (int u = t; u < CRANGE / 4; u += TPB)
        ((float4*)Lyn)[u] = ((const float4*)(ynorm + cbase0))[u];

    // --- A fragments: X rows (qbase + mt*16 + l15), k = kb*32 + lq*8 + j ---
    half8 ah[4][2], al[4][2];
#pragma unroll
    for (int mt = 0; mt < 4; ++mt) {
#pragma unroll
        for (int kb = 0; kb < 2; ++kb) {
            const float* xp = X + (size_t)(qbase + mt * 16 + l15) * EMB + kb * 32 + lq * 8;
            float4 v0 = *(const float4*)xp;
            float4 v1 = *(const float4*)(xp + 4);
            float xv[8] = {v0.x, v0.y, v0.z, v0.w, v1.x, v1.y, v1.z, v1.w};
            half8 h, l;
#pragma unroll
            for (int j = 0; j < 8; ++j) {
                _Float16 hh = (_Float16)xv[j];
                h[j] = hh;
                l[j] = (_Float16)(xv[j] - (float)hh);
            }
            ah[mt][kb] = h;
            al[mt][kb] = l;
        }
    }

    float minv[4][4];
    int   mini[4][4];
#pragma unroll
    for (int mt = 0; mt < 4; ++mt)
#pragma unroll
        for (int r = 0; r < 4; ++r) { minv[mt][r] = INFINITY; mini[mt][r] = 0; }

    const f32x4 zero4 = {0.f, 0.f, 0.f, 0.f};

    __syncthreads();   // tile0 DMA + Lyn writes visible

    int cur = 0;
    for (int tt = 0; tt < NT; ++tt) {
        // --- STAGE tile tt+1 into the other buffer (async DMA, in flight under MFMAs) ---
        if (tt + 1 < NT) {
            const size_t gsbase = (size_t)((cbase0 + (tt + 1) * TILE_C) >> 4) * 1024;
            _Float16* dH = (cur ^ 1) ? LdsH1 : LdsH0;
            _Float16* dL = (cur ^ 1) ? LdsL1 : LdsL0;
#pragma unroll
            for (int i = 0; i < 4; ++i) {
                const int jw = i * 256 + wid * 64;
                gl2lds16(Wh + gsbase + (size_t)(jw + lane) * 8, dH + (size_t)jw * 8);
                gl2lds16(Wl + gsbase + (size_t)(jw + lane) * 8, dL + (size_t)jw * 8);
            }
        }

        // --- COMPUTE tile tt from buf cur, ct-loop software-pipelined ---
        const _Float16* LH = cur ? LdsH1 : LdsH0;
        const _Float16* LL = cur ? LdsL1 : LdsL0;
        const int c0 = tt * TILE_C;

        // preload ct=0 B-fragments
        int chunk0 = (wy * 4) * 128 + lane;
        half8 bh0 = *(const half8*)(LH + (size_t)chunk0 * 8);
        half8 bl0 = *(const half8*)(LL + (size_t)chunk0 * 8);
        half8 bh1 = *(const half8*)(LH + (size_t)(chunk0 + 64) * 8);
        half8 bl1 = *(const half8*)(LL + (size_t)(chunk0 + 64) * 8);

#pragma unroll
        for (int ct = 0; ct < 4; ++ct) {
            f32x4 acc[4];
            __builtin_amdgcn_s_setprio(1);
#pragma unroll
            for (int mt = 0; mt < 4; ++mt) {
                f32x4 a = __builtin_amdgcn_mfma_f32_16x16x32_f16(al[mt][0], bl0, zero4, 0, 0, 0);
                a = __builtin_amdgcn_mfma_f32_16x16x32_f16(al[mt][0], bh0, a, 0, 0, 0);
                a = __builtin_amdgcn_mfma_f32_16x16x32_f16(ah[mt][0], bl0, a, 0, 0, 0);
                a = __builtin_amdgcn_mfma_f32_16x16x32_f16(ah[mt][0], bh0, a, 0, 0, 0);
                a = __builtin_amdgcn_mfma_f32_16x16x32_f16(al[mt][1], bl1, a, 0, 0, 0);
                a = __builtin_amdgcn_mfma_f32_16x16x32_f16(al[mt][1], bh1, a, 0, 0, 0);
                a = __builtin_amdgcn_mfma_f32_16x16x32_f16(ah[mt][1], bl1, a, 0, 0, 0);
                a = __builtin_amdgcn_mfma_f32_16x16x32_f16(ah[mt][1], bh1, a, 0, 0, 0);
                acc[mt] = a;
            }
            __builtin_amdgcn_s_setprio(0);

            // prefetch next ct's B-fragments: ds_read latency hides under epilogue
            if (ct < 3) {
                const int cn = (wy * 4 + ct + 1) * 128 + lane;
                bh0 = *(const half8*)(LH + (size_t)cn * 8);
                bl0 = *(const half8*)(LL + (size_t)cn * 8);
                bh1 = *(const half8*)(LH + (size_t)(cn + 64) * 8);
                bl1 = *(const half8*)(LL + (size_t)(cn + 64) * 8);
            }

            // --- epilogue: dist = ynorm - 2*dot; running argmin (c ascending, strict <) ---
            const int   ccol = wy * 64 + ct * 16;
            const float yn   = Lyn[c0 + ccol + l15];
            const int   cidx = cbase0 + c0 + ccol + l15;
#pragma unroll
            for (int mt = 0; mt < 4; ++mt) {
#pragma unroll
                for (int r = 0; r < 4; ++r) {
                    float s = fmaf(-2.f, acc[mt][r], yn);
                    if (s < minv[mt][r]) { minv[mt][r] = s; mini[mt][r] = cidx; }
                }
            }
        }

        // --- drain: tile tt+1 DMA has been landing under the MFMAs above ---
        asm volatile("s_waitcnt vmcnt(0)" ::: "memory");
        asm volatile("s_waitcnt lgkmcnt(0)" ::: "memory");
        __builtin_amdgcn_s_barrier();
        cur ^= 1;
    }

    // --- cross-lane: reduce over the 16 col-lanes (xor on low 4 lane bits) ---
#pragma unroll
    for (int mt = 0; mt < 4; ++mt) {
#pragma unroll
        for (int r = 0; r < 4; ++r) {
            float v = minv[mt][r];
            int   i = mini[mt][r];
#pragma unroll
            for (int m = 1; m <= 8; m <<= 1) {
                float ov = __shfl_xor(v, m, 64);
                int   oi = __shfl_xor(i, m, 64);
                if (ov < v || (ov == v && oi < i)) { v = ov; i = oi; }
            }
            if (l15 == 0) {
                int qoff = wq * 64 + mt * 16 + lq * 4 + r;   // row within block
                RedV[wy][qoff] = v;
                RedI[wy][qoff] = i;
            }
        }
    }
    __syncthreads();

    // --- combine the two c-halves, write per-split partial ---
    if (t < BQ) {
        float v0 = RedV[0][t]; int i0 = RedI[0][t];
        float v1 = RedV[1][t]; int i1 = RedI[1][t];
        if (v1 < v0 || (v1 == v0 && i1 < i0)) { v0 = v1; i0 = i1; }
        size_t o = (size_t)by * NQ + qblk + t;
        pval[o] = v0;
        pidx[o] = i0;
    }
}

// ---------------------------------------------------------------------------
// Combine phase: CSPLIT partials -> final int32 indices
// ---------------------------------------------------------------------------
__device__ __forceinline__ void vq_combine_phase(
    int q, const float* __restrict__ pval, const int* __restrict__ pidx,
    int* __restrict__ out)
{
    if (q >= NQ) return;
    float bv = pval[q];
    int   bi = pidx[q];
#pragma unroll
    for (int s = 1; s < CSPLIT; ++s) {
        float v  = pval[(size_t)s * NQ + q];
        int   i2 = pidx[(size_t)s * NQ + q];
        if (v < bv || (v == bv && i2 < bi)) { bv = v; bi = i2; }
    }
    out[q] = bi;
}

// ---------------------------------------------------------------------------
// Fused cooperative kernel: prep -> grid.sync -> main -> grid.sync -> combine.
// Grid = 512 blocks (2/CU x 256 CU co-resident at 74KB LDS).
// ---------------------------------------------------------------------------
__global__ __launch_bounds__(TPB, 2) void vq_coop_kernel(
    const float* __restrict__ X, const float* __restrict__ W,
    _Float16* __restrict__ Wh, _Float16* __restrict__ Wl,
    float* __restrict__ ynorm,
    float* __restrict__ pval, int* __restrict__ pidx, int* __restrict__ out)
{
    cg::grid_group grid = cg::this_grid();
    const int gtid = blockIdx.x * TPB + threadIdx.x;

    vq_prep_phase(gtid, W, Wh, Wl, ynorm);
    __threadfence();
    grid.sync();

    vq_main_phase(blockIdx.x & (NXBLK - 1), blockIdx.x >> 7,
                  X, Wh, Wl, ynorm, pval, pidx);
    __threadfence();
    grid.sync();

    vq_combine_phase(gtid, pval, pidx, out);
}

// --- fallback (non-cooperative) path: identical phase code, 3 launches ---
__global__ void prep_kernel_f(const float* __restrict__ W,
                              _Float16* __restrict__ Wh, _Float16* __restrict__ Wl,
                              float* __restrict__ ynorm) {
    vq_prep_phase(blockIdx.x * 256 + threadIdx.x, W, Wh, Wl, ynorm);
}
__global__ __launch_bounds__(TPB, 2) void vq_main_kernel_f(
    const float* __restrict__ X,
    const _Float16* __restrict__ Wh, const _Float16* __restrict__ Wl,
    const float* __restrict__ ynorm,
    float* __restrict__ pval, int* __restrict__ pidx) {
    vq_main_phase(blockIdx.x, blockIdx.y, X, Wh, Wl, ynorm, pval, pidx);
}
__global__ void combine_kernel_f(const float* __restrict__ pval,
                                 const int* __restrict__ pidx,
                                 int* __restrict__ out) {
    vq_combine_phase(blockIdx.x * 256 + threadIdx.x, pval, pidx, out);
}

// ---------------------------------------------------------------------------
extern "C" void kernel_launch(void* const* d_in, const int* in_sizes, int n_in,
                              void* d_out, int out_size, void* d_ws, size_t ws_size,
                              hipStream_t stream) {
    const float* X = (const float*)d_in[0];   // [16384, 64]
    const float* W = (const float*)d_in[1];   // [8192, 64]

    // ws layout: Wh(1MB) | Wl(1MB) | ynorm(32KB) | pval(256KB) | pidx(256KB)
    _Float16* Wh    = (_Float16*)d_ws;
    _Float16* Wl    = Wh + (size_t)NTOK * EMB;
    float*    ynorm = (float*)(Wl + (size_t)NTOK * EMB);
    float*    pval  = ynorm + NTOK;
    int*      pidx  = (int*)(pval + (size_t)CSPLIT * NQ);
    int*      out   = (int*)d_out;

    void* args[] = {(void*)&X, (void*)&W, (void*)&Wh, (void*)&Wl,
                    (void*)&ynorm, (void*)&pval, (void*)&pidx, (void*)&out};
    hipError_t e = hipLaunchCooperativeKernel((const void*)vq_coop_kernel,
                                              dim3(NGRID), dim3(TPB),
                                              args, 0, stream);
    if (e != hipSuccess) {
        (void)hipGetLastError();   // clear sticky error, take the 3-launch path
        prep_kernel_f<<<(NTOK * 8 + NTOK) / 256, 256, 0, stream>>>(W, Wh, Wl, ynorm);
        dim3 grid(NXBLK, CSPLIT);
        vq_main_kernel_f<<<grid, TPB, 0, stream>>>(X, Wh, Wl, ynorm, pval, pidx);
        combine_kernel_f<<<NQ / 256, 256, 0, stream>>>(pval, pidx, out);
    }
}

// Round 5
// 154.603 us; speedup vs baseline: 1.9295x; 1.9295x over previous
//
#include <hip/hip_runtime.h>
#include <math.h>

// Problem: X[16384,64] fp32, W[8192,64] fp32 -> argmin_c ||x-w_c||^2 (int32)
#define EMB     64
#define NTOK    8192
#define NQ      16384
#define TPB     256               // 4 waves: 2 q-halves x 2 c-halves
#define CSPLIT  4
#define CRANGE  (NTOK / CSPLIT)   // 2048 codewords per y-split
#define BQ      128               // query rows per block
#define TILE_C  128               // codewords staged in LDS per iteration
#define NT      (CRANGE / TILE_C) // 16 tiles
#define TCH     (TILE_C * EMB)    // halves per tile buffer (8192 = 16KB)
#define NXBLK   (NQ / BQ)         // 128

typedef _Float16 half8 __attribute__((ext_vector_type(8)));
typedef float    f32x4 __attribute__((ext_vector_type(4)));

// async global->LDS DMA, 16B per lane (dest = wave-uniform base + lane*16)
__device__ __forceinline__ void gl2lds16(const _Float16* g, _Float16* l) {
    __builtin_amdgcn_global_load_lds(
        (const __attribute__((address_space(1))) unsigned int*)g,
        (__attribute__((address_space(3))) unsigned int*)l, 16, 0, 0);
}

// ---------------------------------------------------------------------------
// Fused prep (verified r3): ||w_c||^2 fp32 + split W into fp16 hi/lo in
// MFMA-FRAGMENT ORDER. Chunk u (16B): u = g*128 + kb*64 + lq*16 + r,
// c = g*16+r, k0 = kb*32+lq*8. A wave reading (group g, half kb) touches 64
// consecutive chunks -> linear global_load_lds + conflict-free ds_read_b128.
// ---------------------------------------------------------------------------
__global__ void prep_kernel(const float* __restrict__ W,
                            _Float16* __restrict__ Wh, _Float16* __restrict__ Wl,
                            float* __restrict__ ynorm) {
    int c = blockIdx.x * blockDim.x + threadIdx.x;   // 0..NTOK-1
    if (c >= NTOK) return;
    const int g = c >> 4, r = c & 15;
    const float* wp = W + (size_t)c * EMB;
    float s = 0.f;
#pragma unroll
    for (int seg = 0; seg < 8; ++seg) {              // seg = kb*4 + lq
        float4 v0 = *(const float4*)(wp + seg * 8);
        float4 v1 = *(const float4*)(wp + seg * 8 + 4);
        float xv[8] = {v0.x, v0.y, v0.z, v0.w, v1.x, v1.y, v1.z, v1.w};
        half8 h, l;
#pragma unroll
        for (int j = 0; j < 8; ++j) {
            _Float16 hh = (_Float16)xv[j];
            h[j] = hh;
            l[j] = (_Float16)(xv[j] - (float)hh);
            s = fmaf(xv[j], xv[j], s);
        }
        const int kb = seg >> 2, lq = seg & 3;
        const size_t u = (size_t)g * 128 + kb * 64 + lq * 16 + r;
        *(half8*)(Wh + u * 8) = h;
        *(half8*)(Wl + u * 8) = l;
    }
    ynorm[c] = s;
}

// ---------------------------------------------------------------------------
// Main: fp16 3-TERM split MFMA distance + argmin, 2-phase pipelined staging,
// with fused finisher-combine (split-K pattern).
// Round-1 winning shape: 4 waves = 2(q-half: 64 rows) x 2(c-half: 64 cols).
// 3-term: dot ~= ah*bh + ah*bl + al*bh (dropped al*bl <= 2^-22 rel ~ 2e-6
// abs on distances with O(0.1..1) argmin margins; 4-term already passed with
// absmax=0 while deviating ~1e-5 from the fp32 reference).
// __launch_bounds__ NOTE (measured r2/r3): hipcc arg2 = min WORKGROUPS/CU.
// (256,3) -> cap ~170 VGPR; kernel uses ~124. Coop-launch fusion measured
// 3x SLOWER (r4: 237us, MfmaUtil 11.5%) -- do not re-try grid.sync here.
// ---------------------------------------------------------------------------
__global__ __launch_bounds__(TPB, 3) void vq_mfma_kernel(
    const float* __restrict__ X,
    const _Float16* __restrict__ Wh, const _Float16* __restrict__ Wl,
    const float* __restrict__ ynorm,
    float* __restrict__ pval, int* __restrict__ pidx,
    int* __restrict__ cnt, int* __restrict__ out)
{
    __shared__ __align__(16) _Float16 LdsH0[TCH];
    __shared__ __align__(16) _Float16 LdsH1[TCH];
    __shared__ __align__(16) _Float16 LdsL0[TCH];
    __shared__ __align__(16) _Float16 LdsL1[TCH];
    __shared__ __align__(16) float    Lyn[CRANGE];
    __shared__ float RedV[2][BQ];
    __shared__ int   RedI[2][BQ];
    __shared__ int   fin;

    const int t    = threadIdx.x;
    const int lane = t & 63;
    const int wid  = t >> 6;       // 0..3
    const int wq   = wid & 1;      // q half (0/1)
    const int wy   = wid >> 1;     // c half (0/1)
    const int l15  = lane & 15;
    const int lq   = lane >> 4;    // 0..3

    const int bx     = blockIdx.x;
    const int qblk   = bx * BQ;
    const int qbase  = qblk + wq * 64;
    const int cbase0 = blockIdx.y * CRANGE;

    // --- issue tile-0 DMA first so it overlaps prologue work ---
    {
        const size_t gsbase = (size_t)(cbase0 >> 4) * 1024;   // halves
#pragma unroll
        for (int i = 0; i < 4; ++i) {
            const int jw = i * 256 + wid * 64;                // wave-uniform chunk base
            gl2lds16(Wh + gsbase + (size_t)(jw + lane) * 8, LdsH0 + (size_t)jw * 8);
            gl2lds16(Wl + gsbase + (size_t)(jw + lane) * 8, LdsL0 + (size_t)jw * 8);
        }
    }

    // --- stage the block's full ynorm range once ---
    for (int u = t; u < CRANGE / 4; u += TPB)
        ((float4*)Lyn)[u] = ((const float4*)(ynorm + cbase0))[u];

    // --- A fragments: X rows (qbase + mt*16 + l15), k = kb*32 + lq*8 + j ---
    half8 ah[4][2], al[4][2];
#pragma unroll
    for (int mt = 0; mt < 4; ++mt) {
#pragma unroll
        for (int kb = 0; kb < 2; ++kb) {
            const float* xp = X + (size_t)(qbase + mt * 16 + l15) * EMB + kb * 32 + lq * 8;
            float4 v0 = *(const float4*)xp;
            float4 v1 = *(const float4*)(xp + 4);
            float xv[8] = {v0.x, v0.y, v0.z, v0.w, v1.x, v1.y, v1.z, v1.w};
            half8 h, l;
#pragma unroll
            for (int j = 0; j < 8; ++j) {
                _Float16 hh = (_Float16)xv[j];
                h[j] = hh;
                l[j] = (_Float16)(xv[j] - (float)hh);
            }
            ah[mt][kb] = h;
            al[mt][kb] = l;
        }
    }

    float minv[4][4];
    int   mini[4][4];
#pragma unroll
    for (int mt = 0; mt < 4; ++mt)
#pragma unroll
        for (int r = 0; r < 4; ++r) { minv[mt][r] = INFINITY; mini[mt][r] = 0; }

    const f32x4 zero4 = {0.f, 0.f, 0.f, 0.f};

    __syncthreads();   // tile0 DMA + Lyn writes visible

    int cur = 0;
    for (int tt = 0; tt < NT; ++tt) {
        // --- STAGE tile tt+1 into the other buffer (async DMA, in flight under MFMAs) ---
        if (tt + 1 < NT) {
            const size_t gsbase = (size_t)((cbase0 + (tt + 1) * TILE_C) >> 4) * 1024;
            _Float16* dH = (cur ^ 1) ? LdsH1 : LdsH0;
            _Float16* dL = (cur ^ 1) ? LdsL1 : LdsL0;
#pragma unroll
            for (int i = 0; i < 4; ++i) {
                const int jw = i * 256 + wid * 64;
                gl2lds16(Wh + gsbase + (size_t)(jw + lane) * 8, dH + (size_t)jw * 8);
                gl2lds16(Wl + gsbase + (size_t)(jw + lane) * 8, dL + (size_t)jw * 8);
            }
        }

        // --- COMPUTE tile tt from buf cur ---
        const _Float16* LH = cur ? LdsH1 : LdsH0;
        const _Float16* LL = cur ? LdsL1 : LdsL0;
        const int c0 = tt * TILE_C;
#pragma unroll
        for (int ct = 0; ct < 4; ++ct) {
            const int chunk0 = (wy * 4 + ct) * 128 + lane;   // 64 consecutive chunks/wave
            half8 bh0 = *(const half8*)(LH + (size_t)chunk0 * 8);
            half8 bl0 = *(const half8*)(LL + (size_t)chunk0 * 8);
            half8 bh1 = *(const half8*)(LH + (size_t)(chunk0 + 64) * 8);
            half8 bl1 = *(const half8*)(LL + (size_t)(chunk0 + 64) * 8);
            f32x4 acc[4];
#pragma unroll
            for (int mt = 0; mt < 4; ++mt) {
                // 3-term: al*bh + ah*bl + ah*bh per kb (al*bl dropped)
                f32x4 a = __builtin_amdgcn_mfma_f32_16x16x32_f16(al[mt][0], bh0, zero4, 0, 0, 0);
                a = __builtin_amdgcn_mfma_f32_16x16x32_f16(ah[mt][0], bl0, a, 0, 0, 0);
                a = __builtin_amdgcn_mfma_f32_16x16x32_f16(ah[mt][0], bh0, a, 0, 0, 0);
                a = __builtin_amdgcn_mfma_f32_16x16x32_f16(al[mt][1], bh1, a, 0, 0, 0);
                a = __builtin_amdgcn_mfma_f32_16x16x32_f16(ah[mt][1], bl1, a, 0, 0, 0);
                a = __builtin_amdgcn_mfma_f32_16x16x32_f16(ah[mt][1], bh1, a, 0, 0, 0);
                acc[mt] = a;
            }
            // --- epilogue: dist = ynorm - 2*dot; running argmin (c ascending, strict <) ---
            const int   ccol = wy * 64 + ct * 16;
            const float yn   = Lyn[c0 + ccol + l15];
            const int   cidx = cbase0 + c0 + ccol + l15;
#pragma unroll
            for (int mt = 0; mt < 4; ++mt) {
#pragma unroll
                for (int r = 0; r < 4; ++r) {
                    float s = fmaf(-2.f, acc[mt][r], yn);
                    if (s < minv[mt][r]) { minv[mt][r] = s; mini[mt][r] = cidx; }
                }
            }
        }

        // --- drain: tile tt+1 DMA has been landing under the MFMAs above ---
        asm volatile("s_waitcnt vmcnt(0)" ::: "memory");
        asm volatile("s_waitcnt lgkmcnt(0)" ::: "memory");
        __builtin_amdgcn_s_barrier();
        cur ^= 1;
    }

    // --- cross-lane: reduce over the 16 col-lanes (xor on low 4 lane bits) ---
#pragma unroll
    for (int mt = 0; mt < 4; ++mt) {
#pragma unroll
        for (int r = 0; r < 4; ++r) {
            float v = minv[mt][r];
            int   i = mini[mt][r];
#pragma unroll
            for (int m = 1; m <= 8; m <<= 1) {
                float ov = __shfl_xor(v, m, 64);
                int   oi = __shfl_xor(i, m, 64);
                if (ov < v || (ov == v && oi < i)) { v = ov; i = oi; }
            }
            if (l15 == 0) {
                int qoff = wq * 64 + mt * 16 + lq * 4 + r;   // row within block
                RedV[wy][qoff] = v;
                RedI[wy][qoff] = i;
            }
        }
    }
    __syncthreads();

    // --- combine the two c-halves, write per-split partial ---
    if (t < BQ) {
        float v0 = RedV[0][t]; int i0 = RedI[0][t];
        float v1 = RedV[1][t]; int i1 = RedI[1][t];
        if (v1 < v0 || (v1 == v0 && i1 < i0)) { v0 = v1; i0 = i1; }
        size_t o = (size_t)blockIdx.y * NQ + qblk + t;
        pval[o] = v0;
        pidx[o] = i0;
    }

    // --- fused finisher-combine (split-K pattern): last split-block for this
    // q-range reads all CSPLIT partials and writes the final indices.
    // cnt[] is zeroed by hipMemsetAsync before this kernel each launch.
    __threadfence();                       // release: partials visible device-wide
    if (t == 0) {
        int old = atomicAdd(&cnt[bx], 1);  // device-scope (G12)
        fin = (old == CSPLIT - 1);
    }
    __syncthreads();
    if (fin) {
        __threadfence();                   // acquire: other splits' partials fresh
        if (t < BQ) {
            const int q = qblk + t;
            float bv = pval[q];
            int   bi = pidx[q];
#pragma unroll
            for (int s = 1; s < CSPLIT; ++s) {
                float v  = pval[(size_t)s * NQ + q];
                int   i2 = pidx[(size_t)s * NQ + q];
                if (v < bv || (v == bv && i2 < bi)) { bv = v; bi = i2; }
            }
            out[q] = bi;
        }
    }
}

// ---------------------------------------------------------------------------
extern "C" void kernel_launch(void* const* d_in, const int* in_sizes, int n_in,
                              void* d_out, int out_size, void* d_ws, size_t ws_size,
                              hipStream_t stream) {
    const float* X = (const float*)d_in[0];   // [16384, 64]
    const float* W = (const float*)d_in[1];   // [8192, 64]

    // ws layout: Wh(1MB) | Wl(1MB) | ynorm(32KB) | pval(256KB) | pidx(256KB) | cnt(512B)
    _Float16* Wh    = (_Float16*)d_ws;
    _Float16* Wl    = Wh + (size_t)NTOK * EMB;
    float*    ynorm = (float*)(Wl + (size_t)NTOK * EMB);
    float*    pval  = ynorm + NTOK;
    int*      pidx  = (int*)(pval + (size_t)CSPLIT * NQ);
    int*      cnt   = pidx + (size_t)CSPLIT * NQ;
    int*      out   = (int*)d_out;

    hipMemsetAsync(cnt, 0, NXBLK * sizeof(int), stream);
    prep_kernel<<<NTOK / TPB, TPB, 0, stream>>>(W, Wh, Wl, ynorm);
    dim3 grid(NXBLK, CSPLIT);
    vq_mfma_kernel<<<grid, TPB, 0, stream>>>(X, Wh, Wl, ynorm, pval, pidx, cnt, out);
}

// Round 6
// 116.631 us; speedup vs baseline: 2.5577x; 1.3256x over previous
//
#include <hip/hip_runtime.h>
#include <math.h>

// Problem: X[16384,64] fp32, W[8192,64] fp32 -> argmin_c ||x-w_c||^2 (int32)
#define EMB     64
#define NTOK    8192
#define NQ      16384
#define TPB     256               // 4 waves: 2 q-halves x 2 c-halves
#define CSPLIT  4
#define CRANGE  (NTOK / CSPLIT)   // 2048 codewords per y-split
#define BQ      128               // query rows per block
#define TILE_C  128               // codewords staged in LDS per iteration
#define NT      (CRANGE / TILE_C) // 16 tiles
#define TCH     (TILE_C * EMB)    // halves per tile buffer (8192 = 16KB)
#define NXBLK   (NQ / BQ)         // 128

typedef _Float16 half8 __attribute__((ext_vector_type(8)));
typedef float    f32x4 __attribute__((ext_vector_type(4)));

// async global->LDS DMA, 16B per lane (dest = wave-uniform base + lane*16)
__device__ __forceinline__ void gl2lds16(const _Float16* g, _Float16* l) {
    __builtin_amdgcn_global_load_lds(
        (const __attribute__((address_space(1))) unsigned int*)g,
        (__attribute__((address_space(3))) unsigned int*)l, 16, 0, 0);
}

// monotone float->uint map: m(a) < m(b) iff a < b (no NaNs here)
__device__ __forceinline__ unsigned long long pack_di(float d, int idx) {
    unsigned int u = __float_as_uint(d);
    unsigned int m = (u & 0x80000000u) ? ~u : (u | 0x80000000u);
    return ((unsigned long long)m << 32) | (unsigned int)idx;
}

// ---------------------------------------------------------------------------
// Fused prep (verified r3): ||w_c||^2 fp32 + split W into fp16 hi/lo in
// MFMA-FRAGMENT ORDER, + init of packed[] / cnt[] (replaces memset dispatch).
// Chunk u (16B): u = g*128 + kb*64 + lq*16 + r, c = g*16+r, k0 = kb*32+lq*8.
// A wave reading (group g, half kb) touches 64 consecutive chunks -> linear
// global_load_lds + conflict-free ds_read_b128.
// ---------------------------------------------------------------------------
__global__ void prep_kernel(const float* __restrict__ W,
                            _Float16* __restrict__ Wh, _Float16* __restrict__ Wl,
                            float* __restrict__ ynorm,
                            unsigned long long* __restrict__ packed,
                            int* __restrict__ cnt) {
    const int gtid = blockIdx.x * blockDim.x + threadIdx.x;   // 0..NQ-1 (grid=NQ)
    if (gtid < NQ)    packed[gtid] = ~0ull;
    if (gtid < NXBLK) cnt[gtid] = 0;
    if (gtid >= NTOK) return;
    const int c = gtid;
    const int g = c >> 4, r = c & 15;
    const float* wp = W + (size_t)c * EMB;
    float s = 0.f;
#pragma unroll
    for (int seg = 0; seg < 8; ++seg) {              // seg = kb*4 + lq
        float4 v0 = *(const float4*)(wp + seg * 8);
        float4 v1 = *(const float4*)(wp + seg * 8 + 4);
        float xv[8] = {v0.x, v0.y, v0.z, v0.w, v1.x, v1.y, v1.z, v1.w};
        half8 h, l;
#pragma unroll
        for (int j = 0; j < 8; ++j) {
            _Float16 hh = (_Float16)xv[j];
            h[j] = hh;
            l[j] = (_Float16)(xv[j] - (float)hh);
            s = fmaf(xv[j], xv[j], s);
        }
        const int kb = seg >> 2, lq = seg & 3;
        const size_t u = (size_t)g * 128 + kb * 64 + lq * 16 + r;
        *(half8*)(Wh + u * 8) = h;
        *(half8*)(Wl + u * 8) = l;
    }
    ynorm[c] = s;
}

// ---------------------------------------------------------------------------
// Main: fp16 3-TERM split MFMA distance + argmin (round-1 verified shape:
// 4 waves = 2 q-halves x 2 c-halves, 2-phase async-DMA pipeline), ending in a
// FENCE-FREE atomic combine: atomicMin on packed (dist,idx) u64 + waitcnt +
// ticket; last split-block extracts out[]. All cross-block traffic is
// device-scope atomics (coherent, G12/m20) -> NO __threadfence.
// Measured session notes:
//  - __launch_bounds__ arg2 = min WORKGROUPS/CU (r2: (512,4) => 64-VGPR spill).
//  - coop grid.sync fusion: 3x slower (r4, 237us). Do not re-try.
//  - __threadfence finisher: +34us wbl2 storm (r5). Do not re-try.
//  - 3-term split numerics verified r5 (absmax=0).
// ---------------------------------------------------------------------------
__global__ __launch_bounds__(TPB, 3) void vq_mfma_kernel(
    const float* __restrict__ X,
    const _Float16* __restrict__ Wh, const _Float16* __restrict__ Wl,
    const float* __restrict__ ynorm,
    unsigned long long* __restrict__ packed,
    int* __restrict__ cnt, int* __restrict__ out)
{
    __shared__ __align__(16) _Float16 LdsH0[TCH];
    __shared__ __align__(16) _Float16 LdsH1[TCH];
    __shared__ __align__(16) _Float16 LdsL0[TCH];
    __shared__ __align__(16) _Float16 LdsL1[TCH];
    __shared__ __align__(16) float    Lyn[CRANGE];
    __shared__ float RedV[2][BQ];
    __shared__ int   RedI[2][BQ];
    __shared__ int   fin;

    const int t    = threadIdx.x;
    const int lane = t & 63;
    const int wid  = t >> 6;       // 0..3
    const int wq   = wid & 1;      // q half (0/1)
    const int wy   = wid >> 1;     // c half (0/1)
    const int l15  = lane & 15;
    const int lq   = lane >> 4;    // 0..3

    const int bx     = blockIdx.x;
    const int qblk   = bx * BQ;
    const int qbase  = qblk + wq * 64;
    const int cbase0 = blockIdx.y * CRANGE;

    // --- issue tile-0 DMA first so it overlaps prologue work ---
    {
        const size_t gsbase = (size_t)(cbase0 >> 4) * 1024;   // halves
#pragma unroll
        for (int i = 0; i < 4; ++i) {
            const int jw = i * 256 + wid * 64;                // wave-uniform chunk base
            gl2lds16(Wh + gsbase + (size_t)(jw + lane) * 8, LdsH0 + (size_t)jw * 8);
            gl2lds16(Wl + gsbase + (size_t)(jw + lane) * 8, LdsL0 + (size_t)jw * 8);
        }
    }

    // --- stage the block's full ynorm range once ---
    for (int u = t; u < CRANGE / 4; u += TPB)
        ((float4*)Lyn)[u] = ((const float4*)(ynorm + cbase0))[u];

    // --- A fragments: X rows (qbase + mt*16 + l15), k = kb*32 + lq*8 + j ---
    half8 ah[4][2], al[4][2];
#pragma unroll
    for (int mt = 0; mt < 4; ++mt) {
#pragma unroll
        for (int kb = 0; kb < 2; ++kb) {
            const float* xp = X + (size_t)(qbase + mt * 16 + l15) * EMB + kb * 32 + lq * 8;
            float4 v0 = *(const float4*)xp;
            float4 v1 = *(const float4*)(xp + 4);
            float xv[8] = {v0.x, v0.y, v0.z, v0.w, v1.x, v1.y, v1.z, v1.w};
            half8 h, l;
#pragma unroll
            for (int j = 0; j < 8; ++j) {
                _Float16 hh = (_Float16)xv[j];
                h[j] = hh;
                l[j] = (_Float16)(xv[j] - (float)hh);
            }
            ah[mt][kb] = h;
            al[mt][kb] = l;
        }
    }

    float minv[4][4];
    int   mini[4][4];
#pragma unroll
    for (int mt = 0; mt < 4; ++mt)
#pragma unroll
        for (int r = 0; r < 4; ++r) { minv[mt][r] = INFINITY; mini[mt][r] = 0; }

    const f32x4 zero4 = {0.f, 0.f, 0.f, 0.f};

    __syncthreads();   // tile0 DMA + Lyn writes visible

    int cur = 0;
    for (int tt = 0; tt < NT; ++tt) {
        // --- STAGE tile tt+1 into the other buffer (async DMA, in flight under MFMAs) ---
        if (tt + 1 < NT) {
            const size_t gsbase = (size_t)((cbase0 + (tt + 1) * TILE_C) >> 4) * 1024;
            _Float16* dH = (cur ^ 1) ? LdsH1 : LdsH0;
            _Float16* dL = (cur ^ 1) ? LdsL1 : LdsL0;
#pragma unroll
            for (int i = 0; i < 4; ++i) {
                const int jw = i * 256 + wid * 64;
                gl2lds16(Wh + gsbase + (size_t)(jw + lane) * 8, dH + (size_t)jw * 8);
                gl2lds16(Wl + gsbase + (size_t)(jw + lane) * 8, dL + (size_t)jw * 8);
            }
        }

        // --- COMPUTE tile tt from buf cur ---
        const _Float16* LH = cur ? LdsH1 : LdsH0;
        const _Float16* LL = cur ? LdsL1 : LdsL0;
        const int c0 = tt * TILE_C;
#pragma unroll
        for (int ct = 0; ct < 4; ++ct) {
            const int chunk0 = (wy * 4 + ct) * 128 + lane;   // 64 consecutive chunks/wave
            half8 bh0 = *(const half8*)(LH + (size_t)chunk0 * 8);
            half8 bl0 = *(const half8*)(LL + (size_t)chunk0 * 8);
            half8 bh1 = *(const half8*)(LH + (size_t)(chunk0 + 64) * 8);
            half8 bl1 = *(const half8*)(LL + (size_t)(chunk0 + 64) * 8);
            f32x4 acc[4];
#pragma unroll
            for (int mt = 0; mt < 4; ++mt) {
                // 3-term: al*bh + ah*bl + ah*bh per kb (al*bl dropped; verified r5)
                f32x4 a = __builtin_amdgcn_mfma_f32_16x16x32_f16(al[mt][0], bh0, zero4, 0, 0, 0);
                a = __builtin_amdgcn_mfma_f32_16x16x32_f16(ah[mt][0], bl0, a, 0, 0, 0);
                a = __builtin_amdgcn_mfma_f32_16x16x32_f16(ah[mt][0], bh0, a, 0, 0, 0);
                a = __builtin_amdgcn_mfma_f32_16x16x32_f16(al[mt][1], bh1, a, 0, 0, 0);
                a = __builtin_amdgcn_mfma_f32_16x16x32_f16(ah[mt][1], bl1, a, 0, 0, 0);
                a = __builtin_amdgcn_mfma_f32_16x16x32_f16(ah[mt][1], bh1, a, 0, 0, 0);
                acc[mt] = a;
            }
            // --- epilogue: dist = ynorm - 2*dot; running argmin (c ascending, strict <) ---
            const int   ccol = wy * 64 + ct * 16;
            const float yn   = Lyn[c0 + ccol + l15];
            const int   cidx = cbase0 + c0 + ccol + l15;
#pragma unroll
            for (int mt = 0; mt < 4; ++mt) {
#pragma unroll
                for (int r = 0; r < 4; ++r) {
                    float s = fmaf(-2.f, acc[mt][r], yn);
                    if (s < minv[mt][r]) { minv[mt][r] = s; mini[mt][r] = cidx; }
                }
            }
        }

        // --- drain: tile tt+1 DMA has been landing under the MFMAs above ---
        asm volatile("s_waitcnt vmcnt(0)" ::: "memory");
        asm volatile("s_waitcnt lgkmcnt(0)" ::: "memory");
        __builtin_amdgcn_s_barrier();
        cur ^= 1;
    }

    // --- cross-lane: reduce over the 16 col-lanes (xor on low 4 lane bits) ---
#pragma unroll
    for (int mt = 0; mt < 4; ++mt) {
#pragma unroll
        for (int r = 0; r < 4; ++r) {
            float v = minv[mt][r];
            int   i = mini[mt][r];
#pragma unroll
            for (int m = 1; m <= 8; m <<= 1) {
                float ov = __shfl_xor(v, m, 64);
                int   oi = __shfl_xor(i, m, 64);
                if (ov < v || (ov == v && oi < i)) { v = ov; i = oi; }
            }
            if (l15 == 0) {
                int qoff = wq * 64 + mt * 16 + lq * 4 + r;   // row within block
                RedV[wy][qoff] = v;
                RedI[wy][qoff] = i;
            }
        }
    }
    __syncthreads();

    // --- combine c-halves, then FENCE-FREE cross-split combine via atomics ---
    if (t < BQ) {
        float v0 = RedV[0][t]; int i0 = RedI[0][t];
        float v1 = RedV[1][t]; int i1 = RedI[1][t];
        if (v1 < v0 || (v1 == v0 && i1 < i0)) { v0 = v1; i0 = i1; }
        atomicMin(&packed[qblk + t], pack_di(v0, i0));   // device-scope, coherent
    }
    // ensure this block's atomicMins are globally performed before the ticket
    asm volatile("s_waitcnt vmcnt(0)" ::: "memory");
    __syncthreads();
    if (t == 0) fin = (atomicAdd(&cnt[bx], 1) == CSPLIT - 1);
    __syncthreads();
    if (fin && t < BQ) {
        // atomic read-back (atomicMin with identity) -> final packed value
        unsigned long long v = atomicMin(&packed[qblk + t], ~0ull);
        out[qblk + t] = (int)(unsigned int)(v & 0xFFFFFFFFu);
    }
}

// ---------------------------------------------------------------------------
extern "C" void kernel_launch(void* const* d_in, const int* in_sizes, int n_in,
                              void* d_out, int out_size, void* d_ws, size_t ws_size,
                              hipStream_t stream) {
    const float* X = (const float*)d_in[0];   // [16384, 64]
    const float* W = (const float*)d_in[1];   // [8192, 64]

    // ws layout: Wh(1MB) | Wl(1MB) | ynorm(32KB) | packed(128KB) | cnt(512B)
    _Float16* Wh    = (_Float16*)d_ws;
    _Float16* Wl    = Wh + (size_t)NTOK * EMB;
    float*    ynorm = (float*)(Wl + (size_t)NTOK * EMB);
    unsigned long long* packed = (unsigned long long*)(ynorm + NTOK);
    int*      cnt   = (int*)(packed + NQ);
    int*      out   = (int*)d_out;

    prep_kernel<<<NQ / TPB, TPB, 0, stream>>>(W, Wh, Wl, ynorm, packed, cnt);
    dim3 grid(NXBLK, CSPLIT);
    vq_mfma_kernel<<<grid, TPB, 0, stream>>>(X, Wh, Wl, ynorm, packed, cnt, out);
}